// Round 5
// baseline (3124.631 us; speedup 1.0000x reference)
//
#include <hip/hip_runtime.h>

typedef float f32x4 __attribute__((ext_vector_type(4)));
typedef short s16x8 __attribute__((ext_vector_type(8)));
typedef unsigned short u16;

#define B_    256
#define HW_   196
#define E_    1024
#define H_    1024
#define L_    128
#define T_    48
#define FCOUT 1154   // L + H + 2
#define FCPAD 1216   // next multiple of 64

#define GJOBS 128            // gates tiles: (B/32) x (H/64) = 8 x 16
#define FJOBS 76             // fc tiles:    (B/64) x (FCPAD/64) = 4 x 19
#define NBLK  (GJOBS + FJOBS)

__device__ __forceinline__ u16 f2bf(float x) {
  union { float f; unsigned u; } v; v.f = x;
  unsigned r = v.u + 0x7FFF + ((v.u >> 16) & 1);  // RNE
  return (u16)(r >> 16);
}
__device__ __forceinline__ float sigm(float x) { return 1.f / (1.f + expf(-x)); }

// --- agent-scope (cross-XCD coherent, L2-bypassing sc1) 8-byte h accessors ---
__device__ __forceinline__ uint2 ld_h8(const u16* p) {
  unsigned long long v = __hip_atomic_load((const unsigned long long*)p,
                                           __ATOMIC_RELAXED, __HIP_MEMORY_SCOPE_AGENT);
  union { unsigned long long u; uint2 d; } c; c.u = v; return c.d;
}
__device__ __forceinline__ void st_h8(u16* p, ushort4 s) {
  union { ushort4 s; unsigned long long u; } c; c.s = s;
  __hip_atomic_store((unsigned long long*)p, c.u,
                     __ATOMIC_RELAXED, __HIP_MEMORY_SCOPE_AGENT);
}

// --- persistent-grid barrier (all 204 blocks co-resident: 1 block/CU) ---
__device__ __forceinline__ void gbar(int* cnt, int* gen) {
  __syncthreads();                       // drains vmcnt: h sc1-stores complete
  if (threadIdx.x == 0) {
    int g = __hip_atomic_load(gen, __ATOMIC_RELAXED, __HIP_MEMORY_SCOPE_AGENT);
    int a = __hip_atomic_fetch_add(cnt, 1, __ATOMIC_ACQ_REL, __HIP_MEMORY_SCOPE_AGENT);
    if (a == NBLK - 1) {
      __hip_atomic_store(cnt, 0, __ATOMIC_RELAXED, __HIP_MEMORY_SCOPE_AGENT);
      __hip_atomic_store(gen, g + 1, __ATOMIC_RELEASE, __HIP_MEMORY_SCOPE_AGENT);
    } else {
      while (__hip_atomic_load(gen, __ATOMIC_ACQUIRE, __HIP_MEMORY_SCOPE_AGENT) == g)
        __builtin_amdgcn_s_sleep(2);
    }
  }
  __syncthreads();
}

// ---------------------------------------------------------------------------
// Setup: strided fp32 -> bf16 convert, 4 cols/thread (with zero row padding)
// ---------------------------------------------------------------------------
__global__ __launch_bounds__(256) void cvt_bf16_v4(
    const float* __restrict__ in, u16* __restrict__ out,
    int src_rows, int in_ld, int in_off, int cols4, long total4) {
  long idx = (long)blockIdx.x * 256 + threadIdx.x;
  if (idx >= total4) return;
  int r  = (int)(idx / cols4);
  int c4 = (int)(idx % cols4) * 4;
  f32x4 v = {0.f, 0.f, 0.f, 0.f};
  if (r < src_rows) v = *(const f32x4*)&in[(size_t)r * in_ld + in_off + c4];
  ushort4 o;
  ((u16*)&o)[0] = f2bf(v[0]); ((u16*)&o)[1] = f2bf(v[1]);
  ((u16*)&o)[2] = f2bf(v[2]); ((u16*)&o)[3] = f2bf(v[3]);
  *(ushort4*)&out[idx * 4] = o;
}

// ---------------------------------------------------------------------------
// img_mean[b][e] = mean over HW of image[b][hw][e]; store bf16 (4 e/thread)
// ---------------------------------------------------------------------------
__global__ __launch_bounds__(256) void img_mean_k(
    const float* __restrict__ image, u16* __restrict__ meanB) {
  int idx = blockIdx.x * 256 + threadIdx.x;   // b*(E/4) + e4
  int b  = idx >> 8;                          // E/4 = 256
  int e4 = (idx & 255) * 4;
  const float* p = image + (size_t)b * HW_ * E_ + e4;
  f32x4 s = {0.f, 0.f, 0.f, 0.f};
  #pragma unroll 4
  for (int hw = 0; hw < HW_; ++hw) s += *(const f32x4*)&p[(size_t)hw * E_];
  ushort4 o;
  #pragma unroll
  for (int c = 0; c < 4; ++c) ((u16*)&o)[c] = f2bf(s[c] * (1.0f / HW_));
  *(ushort4*)&meanB[(size_t)b * E_ + e4] = o;
}

// ---------------------------------------------------------------------------
// Setup NT GEMM (64x64 tile, 4 waves of 32x32 via 2x2 16x16x32 mfma).
// MODE 0: outF = acc + bias1[n] + bias2[n]     (gates_base)
// MODE 1: outB = bf16(tanh(acc + bias1[n]))    (h0)
// MODE 2: outF = tanh(acc + bias1[n])          (m0)
// ---------------------------------------------------------------------------
template <int MODE>
__global__ __launch_bounds__(256) void gemm_nt(
    const u16* __restrict__ A, int lda, const u16* __restrict__ Bp, int ldb, int K,
    const float* __restrict__ bias1, const float* __restrict__ bias2,
    float* __restrict__ outF, u16* __restrict__ outB, int ldc) {
  __shared__ __align__(16) u16 As[64][72];
  __shared__ __align__(16) u16 Bs[64][72];

  const int m0 = blockIdx.x * 64;
  const int n0 = blockIdx.y * 64;
  const int tid  = threadIdx.x;
  const int lane = tid & 63;
  const int wave = tid >> 6;
  const int wm = wave & 1, wn = wave >> 1;
  const int quad = lane >> 4, l16 = lane & 15;
  const int loadRow = tid >> 3;
  const int loadCol = (tid & 7) * 8;

  f32x4 acc[2][2] = {};

  for (int kb = 0; kb < K; kb += 64) {
    __syncthreads();
    #pragma unroll
    for (int p = 0; p < 2; ++p) {
      int r = loadRow + p * 32;
      *(uint4*)&As[r][loadCol] = *(const uint4*)&A [(size_t)(m0 + r) * lda + kb + loadCol];
      *(uint4*)&Bs[r][loadCol] = *(const uint4*)&Bp[(size_t)(n0 + r) * ldb + kb + loadCol];
    }
    __syncthreads();
    #pragma unroll
    for (int ks = 0; ks < 64; ks += 32) {
      s16x8 a0v = *(const s16x8*)&As[wm * 32      + l16][ks + quad * 8];
      s16x8 a1v = *(const s16x8*)&As[wm * 32 + 16 + l16][ks + quad * 8];
      s16x8 b0v = *(const s16x8*)&Bs[wn * 32      + l16][ks + quad * 8];
      s16x8 b1v = *(const s16x8*)&Bs[wn * 32 + 16 + l16][ks + quad * 8];
      acc[0][0] = __builtin_amdgcn_mfma_f32_16x16x32_bf16(a0v, b0v, acc[0][0], 0, 0, 0);
      acc[0][1] = __builtin_amdgcn_mfma_f32_16x16x32_bf16(a0v, b1v, acc[0][1], 0, 0, 0);
      acc[1][0] = __builtin_amdgcn_mfma_f32_16x16x32_bf16(a1v, b0v, acc[1][0], 0, 0, 0);
      acc[1][1] = __builtin_amdgcn_mfma_f32_16x16x32_bf16(a1v, b1v, acc[1][1], 0, 0, 0);
    }
  }

  #pragma unroll
  for (int mi = 0; mi < 2; ++mi) {
    #pragma unroll
    for (int ni = 0; ni < 2; ++ni) {
      #pragma unroll
      for (int r = 0; r < 4; ++r) {
        int m = m0 + wm * 32 + mi * 16 + quad * 4 + r;
        int n = n0 + wn * 32 + ni * 16 + l16;
        float v = acc[mi][ni][r];
        if constexpr (MODE == 0) {
          outF[(size_t)m * ldc + n] = v + bias1[n] + bias2[n];
        } else if constexpr (MODE == 1) {
          outB[(size_t)m * ldc + n] = f2bf(tanhf(v + bias1[n]));
        } else {
          outF[(size_t)m * ldc + n] = tanhf(v + bias1[n]);
        }
      }
    }
  }
}

// ---------------------------------------------------------------------------
// R5: PERSISTENT scan kernel. One launch for all T steps; in-kernel grid
// barrier between steps (204 blocks x 512 thr, 113KB LDS -> 1 block/CU,
// all co-resident). Inner K-loops are byte-identical to the verified R2
// structure. Coherence design:
//  * the ONLY cross-block mutable data is h: all h loads/stores use
//    agent-scope atomics (sc1, bypass non-coherent per-XCD L2, land in LLC);
//    __syncthreads' vmcnt drain orders them before the barrier.
//  * mS is block-private forever -> lives in 4 VGPRs/thread (zero traffic).
//  * gbase slice loaded once into LDS; weights/label read-only -> stay
//    L2-warm across all steps (no kernel-boundary invalidation anymore).
//  * jb -> bid%8 mapping co-locates same-jb (same W_hh slice) blocks per XCD.
//  * dead-tile skip (length sorted desc): tiles past their length skip
//    compute; h stays bounded in [-1,1] so stale reads are finite & masked.
// ---------------------------------------------------------------------------
struct GS8 { u16 A[2][32][72]; u16 B[2][256][72]; };   // 82944 B
struct FS8 { u16 A[2][64][72]; u16 B[2][64][72]; };    // 36864 B
union __align__(16) SharedU {
  GS8 g;
  FS8 f;
  float gs[2][4][32][68];                              // 69632 B
  float fs[64][68];                                    // 17408 B
};

__global__ __launch_bounds__(512) void scan_k(
    const u16* __restrict__ labB,    // B x T x L
    const u16* __restrict__ WihL,    // 4H x L
    const u16* __restrict__ WhhB,    // 4H x H
    const u16* __restrict__ WfcB,    // FCPAD x H
    const float* __restrict__ gbase, // B x 4H (includes b_ih + b_hh)
    const float* __restrict__ b_fc,  // FCOUT
    u16* __restrict__ hb0, u16* __restrict__ hb1,
    const float* __restrict__ mS0,   // B x H f32 (m0 from setup)
    const int* __restrict__ length,
    float* __restrict__ out,
    int* __restrict__ barCnt, int* __restrict__ barGen) {
  __shared__ SharedU sh;
  __shared__ __align__(16) float gbs[4][32][64];       // 32768 B

  const int bid  = blockIdx.x;
  const int tid  = threadIdx.x;
  const int g2   = tid >> 8;          // K-half group 0/1
  const int gtid = tid & 255;
  const int lane = tid & 63;
  const int wave = tid >> 6;
  const int sw   = wave & 3;
  const int quad = lane >> 4, l16 = lane & 15;
  const int ar = gtid >> 3;           // load row 0..31
  const int ac = (gtid & 7) * 8;      // load col chunk (u16 units)

  const bool isG = bid < GJOBS;
  int mb = 0, jb = 0, m0 = 0, n0 = 0, glen = 0;
  f32x4 mreg = {0.f, 0.f, 0.f, 0.f};

  if (isG) {
    // bijective: same-jb-pair blocks share bid%8 -> same XCD (heuristic)
    jb = (bid & 7) * 2 + ((bid >> 3) & 1);   // 0..15
    mb = bid >> 4;                           // 0..7
    glen = length[mb * 32];                  // max length in this b-tile
    const int bl = tid >> 4, j4 = (tid & 15) * 4;
    #pragma unroll
    for (int g = 0; g < 4; ++g)
      *(f32x4*)&gbs[g][bl][j4] =
          *(const f32x4*)&gbase[(size_t)(mb * 32 + bl) * (4 * H_) + g * H_ + jb * 64 + j4];
    mreg = *(const f32x4*)&mS0[(size_t)(mb * 32 + bl) * H_ + jb * 64 + j4];
  } else {
    const int fid = bid - GJOBS;
    m0 = (fid / 19) * 64;
    n0 = (fid % 19) * 64;
    glen = length[m0];
  }

  for (int p = 0; p <= T_; ++p) {
    u16* hcur  = (p & 1) ? hb1 : hb0;
    u16* hnext = (p & 1) ? hb0 : hb1;

    if (isG) {
      if (p < T_ && glen > p) {
        // ---------------- gates(p) + LSTM update (R2 inner structure) ------
        f32x4 acc[2][4] = {};
        for (int kb = 0; kb < 9; ++kb) {
          const int seg1 = (g2 == 1) || (kb >= 2);
          const int k0 = g2 ? (448 + kb * 64) : (seg1 ? (kb - 2) * 64 : kb * 64);
          __syncthreads();
          if (seg1) {
            const u16* Ap = hcur + (size_t)(mb * 32 + ar) * H_ + k0 + ac;
            *(uint2*)&sh.g.A[g2][ar][ac]     = ld_h8(Ap);
            *(uint2*)&sh.g.A[g2][ar][ac + 4] = ld_h8(Ap + 4);
          } else {
            *(uint4*)&sh.g.A[g2][ar][ac] = *(const uint4*)
                &labB[(size_t)(mb * 32 + ar) * (T_ * L_) + (size_t)p * L_ + k0 + ac];
          }
          const u16* Bw  = seg1 ? WhhB : WihL;
          const int  ldb = seg1 ? H_ : L_;
          #pragma unroll
          for (int q = 0; q < 8; ++q) {
            int rr = ar + q * 32;                       // 0..255
            int grow = (rr >> 6) * H_ + jb * 64 + (rr & 63);
            *(uint4*)&sh.g.B[g2][rr][ac] =
                *(const uint4*)&Bw[(size_t)grow * ldb + k0 + ac];
          }
          __syncthreads();
          #pragma unroll
          for (int ks = 0; ks < 64; ks += 32) {
            s16x8 av[2], bv[4];
            av[0] = *(const s16x8*)&sh.g.A[g2][l16][ks + quad * 8];
            av[1] = *(const s16x8*)&sh.g.A[g2][16 + l16][ks + quad * 8];
            #pragma unroll
            for (int ni = 0; ni < 4; ++ni)
              bv[ni] = *(const s16x8*)&sh.g.B[g2][sw * 64 + ni * 16 + l16][ks + quad * 8];
            #pragma unroll
            for (int mi = 0; mi < 2; ++mi)
              #pragma unroll
              for (int ni = 0; ni < 4; ++ni)
                acc[mi][ni] = __builtin_amdgcn_mfma_f32_16x16x32_bf16(
                    av[mi], bv[ni], acc[mi][ni], 0, 0, 0);
          }
        }

        __syncthreads();
        #pragma unroll
        for (int mi = 0; mi < 2; ++mi)
          #pragma unroll
          for (int ni = 0; ni < 4; ++ni)
            #pragma unroll
            for (int r = 0; r < 4; ++r)
              sh.gs[g2][sw][mi * 16 + quad * 4 + r][ni * 16 + l16] = acc[mi][ni][r];
        __syncthreads();

        {
          const int bl = tid >> 4, j4 = (tid & 15) * 4;
          f32x4 gi = *(const f32x4*)&sh.gs[0][0][bl][j4] + *(const f32x4*)&sh.gs[1][0][bl][j4];
          f32x4 gf = *(const f32x4*)&sh.gs[0][1][bl][j4] + *(const f32x4*)&sh.gs[1][1][bl][j4];
          f32x4 gg = *(const f32x4*)&sh.gs[0][2][bl][j4] + *(const f32x4*)&sh.gs[1][2][bl][j4];
          f32x4 go = *(const f32x4*)&sh.gs[0][3][bl][j4] + *(const f32x4*)&sh.gs[1][3][bl][j4];
          f32x4 bi  = *(const f32x4*)&gbs[0][bl][j4];
          f32x4 bff = *(const f32x4*)&gbs[1][bl][j4];
          f32x4 bg  = *(const f32x4*)&gbs[2][bl][j4];
          f32x4 bo  = *(const f32x4*)&gbs[3][bl][j4];
          ushort4 hb;
          #pragma unroll
          for (int c = 0; c < 4; ++c) {
            float I = sigm(gi[c] + bi[c]);
            float F = sigm(gf[c] + bff[c]);
            float G = tanhf(gg[c] + bg[c]);
            float O = sigm(go[c] + bo[c]);
            float mm = F * mreg[c] + I * G;
            mreg[c] = mm;
            ((u16*)&hb)[c] = f2bf(O * tanhf(mm));
          }
          st_h8(&hnext[(size_t)(mb * 32 + bl) * H_ + jb * 64 + j4], hb);
        }
      }
    } else if (p >= 1) {
      const int t = p - 1;
      if (glen > t) {
        // ---------------- fc(t) (R2 inner structure) ----------------
        const int wm = sw & 1, wn = sw >> 1;
        f32x4 acc[2][2] = {};
        for (int kb = 0; kb < 8; ++kb) {
          const int k0 = g2 * 512 + kb * 64;
          __syncthreads();
          #pragma unroll
          for (int pp = 0; pp < 2; ++pp) {
            int r = ar + pp * 32;
            const u16* Ap = hcur + (size_t)(m0 + r) * H_ + k0 + ac;
            *(uint2*)&sh.f.A[g2][r][ac]     = ld_h8(Ap);
            *(uint2*)&sh.f.A[g2][r][ac + 4] = ld_h8(Ap + 4);
            *(uint4*)&sh.f.B[g2][r][ac] =
                *(const uint4*)&WfcB[(size_t)(n0 + r) * H_ + k0 + ac];
          }
          __syncthreads();
          #pragma unroll
          for (int ks = 0; ks < 64; ks += 32) {
            s16x8 a0v = *(const s16x8*)&sh.f.A[g2][wm * 32      + l16][ks + quad * 8];
            s16x8 a1v = *(const s16x8*)&sh.f.A[g2][wm * 32 + 16 + l16][ks + quad * 8];
            s16x8 b0v = *(const s16x8*)&sh.f.B[g2][wn * 32      + l16][ks + quad * 8];
            s16x8 b1v = *(const s16x8*)&sh.f.B[g2][wn * 32 + 16 + l16][ks + quad * 8];
            acc[0][0] = __builtin_amdgcn_mfma_f32_16x16x32_bf16(a0v, b0v, acc[0][0], 0, 0, 0);
            acc[0][1] = __builtin_amdgcn_mfma_f32_16x16x32_bf16(a0v, b1v, acc[0][1], 0, 0, 0);
            acc[1][0] = __builtin_amdgcn_mfma_f32_16x16x32_bf16(a1v, b0v, acc[1][0], 0, 0, 0);
            acc[1][1] = __builtin_amdgcn_mfma_f32_16x16x32_bf16(a1v, b1v, acc[1][1], 0, 0, 0);
          }
        }

        __syncthreads();
        if (g2 == 1) {
          #pragma unroll
          for (int mi = 0; mi < 2; ++mi)
            #pragma unroll
            for (int ni = 0; ni < 2; ++ni)
              #pragma unroll
              for (int r = 0; r < 4; ++r)
                sh.fs[wm * 32 + mi * 16 + quad * 4 + r][wn * 32 + ni * 16 + l16] =
                    acc[mi][ni][r];
        }
        __syncthreads();
        if (g2 == 0) {
          #pragma unroll
          for (int mi = 0; mi < 2; ++mi) {
            #pragma unroll
            for (int ni = 0; ni < 2; ++ni) {
              #pragma unroll
              for (int r = 0; r < 4; ++r) {
                int ml = wm * 32 + mi * 16 + quad * 4 + r;
                int nl = wn * 32 + ni * 16 + l16;
                int m = m0 + ml;
                int n = n0 + nl;
                if (n < FCOUT) {
                  float rv = fmaxf(acc[mi][ni][r] + sh.fs[ml][nl] + b_fc[n], 0.f);
                  float msk = (t < length[m]) ? 1.f : 0.f;
                  if (n < L_) {
                    out[(size_t)m * (T_ * L_) + t * L_ + n] = rv * msk;
                  } else if (n < L_ + H_) {
                    out[(size_t)(B_ * T_ * L_) + (size_t)m * (T_ * H_) + t * H_ + (n - L_)] = rv * msk;
                  } else if (n == L_ + H_) {
                    out[(size_t)B_ * T_ * (L_ + H_) + m * T_ + t] = expf(rv) * msk;
                  } else {
                    out[(size_t)B_ * T_ * (L_ + H_ + 1) + m * T_ + t] = sigm(rv) * msk;
                  }
                }
              }
            }
          }
        }
      } else if (n0 == 0) {
        // dead tile: one block per m0 writes the zeros for all outputs
        f32x4 z = {0.f, 0.f, 0.f, 0.f};
        for (int i = tid; i < 64 * 32; i += 512) {          // label: 64 x 128
          int r = i >> 5, c4 = (i & 31) * 4;
          *(f32x4*)&out[(size_t)(m0 + r) * (T_ * L_) + t * L_ + c4] = z;
        }
        for (int i = tid; i < 64 * 256; i += 512) {         // topic: 64 x 1024
          int r = i >> 8, c4 = (i & 255) * 4;
          *(f32x4*)&out[(size_t)(B_ * T_ * L_) + (size_t)(m0 + r) * (T_ * H_) + t * H_ + c4] = z;
        }
        if (tid < 64) {
          out[(size_t)B_ * T_ * (L_ + H_) + (m0 + tid) * T_ + t] = 0.f;
          out[(size_t)B_ * T_ * (L_ + H_ + 1) + (m0 + tid) * T_ + t] = 0.f;
        }
      }
    }

    gbar(barCnt, barGen);
  }
}

// ---------------------------------------------------------------------------
extern "C" void kernel_launch(void* const* d_in, const int* in_sizes, int n_in,
                              void* d_out, int out_size, void* d_ws, size_t ws_size,
                              hipStream_t stream) {
  const float* image  = (const float*)d_in[0];
  const float* label  = (const float*)d_in[1];
  const int*   length = (const int*)  d_in[2];
  const float* W_h    = (const float*)d_in[3];
  const float* b_h    = (const float*)d_in[4];
  const float* W_m    = (const float*)d_in[5];
  const float* b_m    = (const float*)d_in[6];
  const float* W_ih   = (const float*)d_in[7];
  const float* W_hh   = (const float*)d_in[8];
  const float* b_ih   = (const float*)d_in[9];
  const float* b_hh   = (const float*)d_in[10];
  const float* W_fc   = (const float*)d_in[11];
  const float* b_fc   = (const float*)d_in[12];
  float* out = (float*)d_out;

  char* ws = (char*)d_ws;
  size_t off = 0;
  auto alloc = [&](size_t bytes) -> void* {
    void* p = ws + off;
    off = (off + bytes + 255) & ~(size_t)255;
    return p;
  };
  u16*   meanB = (u16*)  alloc((size_t)B_ * E_ * 2);
  u16*   WhB   = (u16*)  alloc((size_t)H_ * E_ * 2);
  u16*   WmB   = (u16*)  alloc((size_t)H_ * E_ * 2);
  u16*   WihE  = (u16*)  alloc((size_t)4 * H_ * E_ * 2);
  u16*   WihL  = (u16*)  alloc((size_t)4 * H_ * L_ * 2);
  u16*   WhhB  = (u16*)  alloc((size_t)4 * H_ * H_ * 2);
  u16*   WfcB  = (u16*)  alloc((size_t)FCPAD * H_ * 2);
  u16*   labB  = (u16*)  alloc((size_t)B_ * T_ * L_ * 2);
  float* gbase = (float*)alloc((size_t)B_ * 4 * H_ * 4);
  u16*   hbuf0 = (u16*)  alloc((size_t)B_ * H_ * 2);
  u16*   hbuf1 = (u16*)  alloc((size_t)B_ * H_ * 2);
  float* mS    = (float*)alloc((size_t)B_ * H_ * 4);
  int*   bar   = (int*)  alloc(256);

  auto cvt = [&](const float* in, u16* o, int rows, int src_rows, int in_ld,
                 int in_off, int cols) {
    long total4 = (long)rows * cols / 4;
    int blocks = (int)((total4 + 255) / 256);
    cvt_bf16_v4<<<blocks, 256, 0, stream>>>(in, o, src_rows, in_ld, in_off,
                                            cols / 4, total4);
  };

  // --- setup: weight/label conversion to bf16 ---
  cvt(W_h,  WhB,  H_,     H_,     E_,      0,  E_);
  cvt(W_m,  WmB,  H_,     H_,     E_,      0,  E_);
  cvt(W_ih, WihE, 4 * H_, 4 * H_, E_ + L_, 0,  E_);   // columns [0, E)
  cvt(W_ih, WihL, 4 * H_, 4 * H_, E_ + L_, E_, L_);   // columns [E, E+L)
  cvt(W_hh, WhhB, 4 * H_, 4 * H_, H_,      0,  H_);
  cvt(W_fc, WfcB, FCPAD,  FCOUT,  H_,      0,  H_);   // zero-padded rows
  cvt(label, labB, B_, B_, T_ * L_, 0, T_ * L_);

  img_mean_k<<<(B_ * E_ / 4) / 256, 256, 0, stream>>>(image, meanB);

  // --- setup GEMMs ---
  gemm_nt<1><<<dim3(B_ / 64, H_ / 64), 256, 0, stream>>>(
      meanB, E_, WhB, E_, E_, b_h, nullptr, nullptr, hbuf0, H_);
  gemm_nt<2><<<dim3(B_ / 64, H_ / 64), 256, 0, stream>>>(
      meanB, E_, WmB, E_, E_, b_m, nullptr, mS, nullptr, H_);
  gemm_nt<0><<<dim3(B_ / 64, (4 * H_) / 64), 256, 0, stream>>>(
      meanB, E_, WihE, E_, E_, b_ih, b_hh, gbase, nullptr, 4 * H_);

  // --- barrier state init + persistent scan (single launch) ---
  hipMemsetAsync(bar, 0, 8, stream);
  scan_k<<<NBLK, 512, 0, stream>>>(
      labB, WihL, WhhB, WfcB, gbase, b_fc, hbuf0, hbuf1, mS, length, out,
      bar, bar + 1);
}

// Round 6
// 1402.754 us; speedup vs baseline: 2.2275x; 2.2275x over previous
//
#include <hip/hip_runtime.h>

typedef float f32x4 __attribute__((ext_vector_type(4)));
typedef short s16x8 __attribute__((ext_vector_type(8)));
typedef unsigned short u16;

#define B_    256
#define HW_   196
#define E_    1024
#define H_    1024
#define L_    128
#define T_    48
#define FCOUT 1154   // L + H + 2
#define FCPAD 1216   // next multiple of 64

#define GJOBS 128            // gates tiles: (B/32) x (H/64) = 8 x 16
#define FJOBS 76             // fc tiles:    (B/64) x (FCPAD/64) = 4 x 19
#define NBLK  (GJOBS + FJOBS)

__device__ __forceinline__ u16 f2bf(float x) {
  union { float f; unsigned u; } v; v.f = x;
  unsigned r = v.u + 0x7FFF + ((v.u >> 16) & 1);  // RNE
  return (u16)(r >> 16);
}
__device__ __forceinline__ float sigm(float x) { return 1.f / (1.f + expf(-x)); }

// --- agent-scope (cross-XCD coherent, L2-bypassing sc1) 8-byte h accessors ---
__device__ __forceinline__ uint2 ld_h8(const u16* p) {
  unsigned long long v = __hip_atomic_load((const unsigned long long*)p,
                                           __ATOMIC_RELAXED, __HIP_MEMORY_SCOPE_AGENT);
  union { unsigned long long u; uint2 d; } c; c.u = v; return c.d;
}
__device__ __forceinline__ void st_h8(u16* p, ushort4 s) {
  union { ushort4 s; unsigned long long u; } c; c.s = s;
  __hip_atomic_store((unsigned long long*)p, c.u,
                     __ATOMIC_RELAXED, __HIP_MEMORY_SCOPE_AGENT);
}

// --- persistent-grid barrier, INVALIDATE-FREE (R6) ---
// All atomics RELAXED: no buffer_inv / buffer_wbl2 is ever emitted, so the
// per-XCD L2s keep the read-only weights warm across all scan steps.
// Monotonic counter, no reset (barrier `it` passed when cnt == NBLK*(it+1)):
// removes the counter-reuse race. Ordering: __syncthreads drains vmcnt so
// each block's sc1 h-stores are LLC-complete before its fetch_add; pollers
// read cnt at the LLC (sc1) and issue their sc1 h-loads only after.
__device__ __forceinline__ void gbar(int* cnt, int it) {
  __syncthreads();                       // vmcnt drain: h sc1-stores complete
  if (threadIdx.x == 0) {
    __hip_atomic_fetch_add(cnt, 1, __ATOMIC_RELAXED, __HIP_MEMORY_SCOPE_AGENT);
    const int target = NBLK * (it + 1);
    while (__hip_atomic_load(cnt, __ATOMIC_RELAXED, __HIP_MEMORY_SCOPE_AGENT) < target)
      __builtin_amdgcn_s_sleep(2);
  }
  __syncthreads();
}

// ---------------------------------------------------------------------------
// Setup: strided fp32 -> bf16 convert, 4 cols/thread (with zero row padding)
// ---------------------------------------------------------------------------
__global__ __launch_bounds__(256) void cvt_bf16_v4(
    const float* __restrict__ in, u16* __restrict__ out,
    int src_rows, int in_ld, int in_off, int cols4, long total4) {
  long idx = (long)blockIdx.x * 256 + threadIdx.x;
  if (idx >= total4) return;
  int r  = (int)(idx / cols4);
  int c4 = (int)(idx % cols4) * 4;
  f32x4 v = {0.f, 0.f, 0.f, 0.f};
  if (r < src_rows) v = *(const f32x4*)&in[(size_t)r * in_ld + in_off + c4];
  ushort4 o;
  ((u16*)&o)[0] = f2bf(v[0]); ((u16*)&o)[1] = f2bf(v[1]);
  ((u16*)&o)[2] = f2bf(v[2]); ((u16*)&o)[3] = f2bf(v[3]);
  *(ushort4*)&out[idx * 4] = o;
}

// ---------------------------------------------------------------------------
// img_mean[b][e] = mean over HW of image[b][hw][e]; store bf16 (4 e/thread)
// ---------------------------------------------------------------------------
__global__ __launch_bounds__(256) void img_mean_k(
    const float* __restrict__ image, u16* __restrict__ meanB) {
  int idx = blockIdx.x * 256 + threadIdx.x;   // b*(E/4) + e4
  int b  = idx >> 8;                          // E/4 = 256
  int e4 = (idx & 255) * 4;
  const float* p = image + (size_t)b * HW_ * E_ + e4;
  f32x4 s = {0.f, 0.f, 0.f, 0.f};
  #pragma unroll 4
  for (int hw = 0; hw < HW_; ++hw) s += *(const f32x4*)&p[(size_t)hw * E_];
  ushort4 o;
  #pragma unroll
  for (int c = 0; c < 4; ++c) ((u16*)&o)[c] = f2bf(s[c] * (1.0f / HW_));
  *(ushort4*)&meanB[(size_t)b * E_ + e4] = o;
}

// ---------------------------------------------------------------------------
// Setup NT GEMM (64x64 tile, 4 waves of 32x32 via 2x2 16x16x32 mfma).
// MODE 0: outF = acc + bias1[n] + bias2[n]     (gates_base)
// MODE 1: outB = bf16(tanh(acc + bias1[n]))    (h0)
// MODE 2: outF = tanh(acc + bias1[n])          (m0)
// ---------------------------------------------------------------------------
template <int MODE>
__global__ __launch_bounds__(256) void gemm_nt(
    const u16* __restrict__ A, int lda, const u16* __restrict__ Bp, int ldb, int K,
    const float* __restrict__ bias1, const float* __restrict__ bias2,
    float* __restrict__ outF, u16* __restrict__ outB, int ldc) {
  __shared__ __align__(16) u16 As[64][72];
  __shared__ __align__(16) u16 Bs[64][72];

  const int m0 = blockIdx.x * 64;
  const int n0 = blockIdx.y * 64;
  const int tid  = threadIdx.x;
  const int lane = tid & 63;
  const int wave = tid >> 6;
  const int wm = wave & 1, wn = wave >> 1;
  const int quad = lane >> 4, l16 = lane & 15;
  const int loadRow = tid >> 3;
  const int loadCol = (tid & 7) * 8;

  f32x4 acc[2][2] = {};

  for (int kb = 0; kb < K; kb += 64) {
    __syncthreads();
    #pragma unroll
    for (int p = 0; p < 2; ++p) {
      int r = loadRow + p * 32;
      *(uint4*)&As[r][loadCol] = *(const uint4*)&A [(size_t)(m0 + r) * lda + kb + loadCol];
      *(uint4*)&Bs[r][loadCol] = *(const uint4*)&Bp[(size_t)(n0 + r) * ldb + kb + loadCol];
    }
    __syncthreads();
    #pragma unroll
    for (int ks = 0; ks < 64; ks += 32) {
      s16x8 a0v = *(const s16x8*)&As[wm * 32      + l16][ks + quad * 8];
      s16x8 a1v = *(const s16x8*)&As[wm * 32 + 16 + l16][ks + quad * 8];
      s16x8 b0v = *(const s16x8*)&Bs[wn * 32      + l16][ks + quad * 8];
      s16x8 b1v = *(const s16x8*)&Bs[wn * 32 + 16 + l16][ks + quad * 8];
      acc[0][0] = __builtin_amdgcn_mfma_f32_16x16x32_bf16(a0v, b0v, acc[0][0], 0, 0, 0);
      acc[0][1] = __builtin_amdgcn_mfma_f32_16x16x32_bf16(a0v, b1v, acc[0][1], 0, 0, 0);
      acc[1][0] = __builtin_amdgcn_mfma_f32_16x16x32_bf16(a1v, b0v, acc[1][0], 0, 0, 0);
      acc[1][1] = __builtin_amdgcn_mfma_f32_16x16x32_bf16(a1v, b1v, acc[1][1], 0, 0, 0);
    }
  }

  #pragma unroll
  for (int mi = 0; mi < 2; ++mi) {
    #pragma unroll
    for (int ni = 0; ni < 2; ++ni) {
      #pragma unroll
      for (int r = 0; r < 4; ++r) {
        int m = m0 + wm * 32 + mi * 16 + quad * 4 + r;
        int n = n0 + wn * 32 + ni * 16 + l16;
        float v = acc[mi][ni][r];
        if constexpr (MODE == 0) {
          outF[(size_t)m * ldc + n] = v + bias1[n] + bias2[n];
        } else if constexpr (MODE == 1) {
          outB[(size_t)m * ldc + n] = f2bf(tanhf(v + bias1[n]));
        } else {
          outF[(size_t)m * ldc + n] = tanhf(v + bias1[n]);
        }
      }
    }
  }
}

// ---------------------------------------------------------------------------
// R6: persistent scan kernel (R5 structure), with the invalidate-free
// barrier. The ONLY change vs R5 is gbar: no acquire/release at agent scope
// anywhere in the loop, so per-XCD L2s keep weights warm across all steps.
// ---------------------------------------------------------------------------
struct GS8 { u16 A[2][32][72]; u16 B[2][256][72]; };   // 82944 B
struct FS8 { u16 A[2][64][72]; u16 B[2][64][72]; };    // 36864 B
union __align__(16) SharedU {
  GS8 g;
  FS8 f;
  float gs[2][4][32][68];                              // 69632 B
  float fs[64][68];                                    // 17408 B
};

__global__ __launch_bounds__(512) void scan_k(
    const u16* __restrict__ labB,    // B x T x L
    const u16* __restrict__ WihL,    // 4H x L
    const u16* __restrict__ WhhB,    // 4H x H
    const u16* __restrict__ WfcB,    // FCPAD x H
    const float* __restrict__ gbase, // B x 4H (includes b_ih + b_hh)
    const float* __restrict__ b_fc,  // FCOUT
    u16* __restrict__ hb0, u16* __restrict__ hb1,
    const float* __restrict__ mS0,   // B x H f32 (m0 from setup)
    const int* __restrict__ length,
    float* __restrict__ out,
    int* __restrict__ barCnt) {
  __shared__ SharedU sh;
  __shared__ __align__(16) float gbs[4][32][64];       // 32768 B

  const int bid  = blockIdx.x;
  const int tid  = threadIdx.x;
  const int g2   = tid >> 8;          // K-half group 0/1
  const int gtid = tid & 255;
  const int lane = tid & 63;
  const int wave = tid >> 6;
  const int sw   = wave & 3;
  const int quad = lane >> 4, l16 = lane & 15;
  const int ar = gtid >> 3;           // load row 0..31
  const int ac = (gtid & 7) * 8;      // load col chunk (u16 units)

  const bool isG = bid < GJOBS;
  int mb = 0, jb = 0, m0 = 0, n0 = 0, glen = 0;
  f32x4 mreg = {0.f, 0.f, 0.f, 0.f};

  if (isG) {
    jb = (bid & 7) * 2 + ((bid >> 3) & 1);   // 0..15
    mb = bid >> 4;                           // 0..7
    glen = length[mb * 32];                  // max length in this b-tile
    const int bl = tid >> 4, j4 = (tid & 15) * 4;
    #pragma unroll
    for (int g = 0; g < 4; ++g)
      *(f32x4*)&gbs[g][bl][j4] =
          *(const f32x4*)&gbase[(size_t)(mb * 32 + bl) * (4 * H_) + g * H_ + jb * 64 + j4];
    mreg = *(const f32x4*)&mS0[(size_t)(mb * 32 + bl) * H_ + jb * 64 + j4];
  } else {
    const int fid = bid - GJOBS;
    m0 = (fid / 19) * 64;
    n0 = (fid % 19) * 64;
    glen = length[m0];
  }

  for (int p = 0; p <= T_; ++p) {
    u16* hcur  = (p & 1) ? hb1 : hb0;
    u16* hnext = (p & 1) ? hb0 : hb1;

    if (isG) {
      if (p < T_ && glen > p) {
        // ---------------- gates(p) + LSTM update (R2 inner structure) ------
        f32x4 acc[2][4] = {};
        for (int kb = 0; kb < 9; ++kb) {
          const int seg1 = (g2 == 1) || (kb >= 2);
          const int k0 = g2 ? (448 + kb * 64) : (seg1 ? (kb - 2) * 64 : kb * 64);
          __syncthreads();
          if (seg1) {
            const u16* Ap = hcur + (size_t)(mb * 32 + ar) * H_ + k0 + ac;
            *(uint2*)&sh.g.A[g2][ar][ac]     = ld_h8(Ap);
            *(uint2*)&sh.g.A[g2][ar][ac + 4] = ld_h8(Ap + 4);
          } else {
            *(uint4*)&sh.g.A[g2][ar][ac] = *(const uint4*)
                &labB[(size_t)(mb * 32 + ar) * (T_ * L_) + (size_t)p * L_ + k0 + ac];
          }
          const u16* Bw  = seg1 ? WhhB : WihL;
          const int  ldb = seg1 ? H_ : L_;
          #pragma unroll
          for (int q = 0; q < 8; ++q) {
            int rr = ar + q * 32;                       // 0..255
            int grow = (rr >> 6) * H_ + jb * 64 + (rr & 63);
            *(uint4*)&sh.g.B[g2][rr][ac] =
                *(const uint4*)&Bw[(size_t)grow * ldb + k0 + ac];
          }
          __syncthreads();
          #pragma unroll
          for (int ks = 0; ks < 64; ks += 32) {
            s16x8 av[2], bv[4];
            av[0] = *(const s16x8*)&sh.g.A[g2][l16][ks + quad * 8];
            av[1] = *(const s16x8*)&sh.g.A[g2][16 + l16][ks + quad * 8];
            #pragma unroll
            for (int ni = 0; ni < 4; ++ni)
              bv[ni] = *(const s16x8*)&sh.g.B[g2][sw * 64 + ni * 16 + l16][ks + quad * 8];
            #pragma unroll
            for (int mi = 0; mi < 2; ++mi)
              #pragma unroll
              for (int ni = 0; ni < 4; ++ni)
                acc[mi][ni] = __builtin_amdgcn_mfma_f32_16x16x32_bf16(
                    av[mi], bv[ni], acc[mi][ni], 0, 0, 0);
          }
        }

        __syncthreads();
        #pragma unroll
        for (int mi = 0; mi < 2; ++mi)
          #pragma unroll
          for (int ni = 0; ni < 4; ++ni)
            #pragma unroll
            for (int r = 0; r < 4; ++r)
              sh.gs[g2][sw][mi * 16 + quad * 4 + r][ni * 16 + l16] = acc[mi][ni][r];
        __syncthreads();

        {
          const int bl = tid >> 4, j4 = (tid & 15) * 4;
          f32x4 gi = *(const f32x4*)&sh.gs[0][0][bl][j4] + *(const f32x4*)&sh.gs[1][0][bl][j4];
          f32x4 gf = *(const f32x4*)&sh.gs[0][1][bl][j4] + *(const f32x4*)&sh.gs[1][1][bl][j4];
          f32x4 gg = *(const f32x4*)&sh.gs[0][2][bl][j4] + *(const f32x4*)&sh.gs[1][2][bl][j4];
          f32x4 go = *(const f32x4*)&sh.gs[0][3][bl][j4] + *(const f32x4*)&sh.gs[1][3][bl][j4];
          f32x4 bi  = *(const f32x4*)&gbs[0][bl][j4];
          f32x4 bff = *(const f32x4*)&gbs[1][bl][j4];
          f32x4 bg  = *(const f32x4*)&gbs[2][bl][j4];
          f32x4 bo  = *(const f32x4*)&gbs[3][bl][j4];
          ushort4 hb;
          #pragma unroll
          for (int c = 0; c < 4; ++c) {
            float I = sigm(gi[c] + bi[c]);
            float F = sigm(gf[c] + bff[c]);
            float G = tanhf(gg[c] + bg[c]);
            float O = sigm(go[c] + bo[c]);
            float mm = F * mreg[c] + I * G;
            mreg[c] = mm;
            ((u16*)&hb)[c] = f2bf(O * tanhf(mm));
          }
          st_h8(&hnext[(size_t)(mb * 32 + bl) * H_ + jb * 64 + j4], hb);
        }
      }
    } else if (p >= 1) {
      const int t = p - 1;
      if (glen > t) {
        // ---------------- fc(t) (R2 inner structure) ----------------
        const int wm = sw & 1, wn = sw >> 1;
        f32x4 acc[2][2] = {};
        for (int kb = 0; kb < 8; ++kb) {
          const int k0 = g2 * 512 + kb * 64;
          __syncthreads();
          #pragma unroll
          for (int pp = 0; pp < 2; ++pp) {
            int r = ar + pp * 32;
            const u16* Ap = hcur + (size_t)(m0 + r) * H_ + k0 + ac;
            *(uint2*)&sh.f.A[g2][r][ac]     = ld_h8(Ap);
            *(uint2*)&sh.f.A[g2][r][ac + 4] = ld_h8(Ap + 4);
            *(uint4*)&sh.f.B[g2][r][ac] =
                *(const uint4*)&WfcB[(size_t)(n0 + r) * H_ + k0 + ac];
          }
          __syncthreads();
          #pragma unroll
          for (int ks = 0; ks < 64; ks += 32) {
            s16x8 a0v = *(const s16x8*)&sh.f.A[g2][wm * 32      + l16][ks + quad * 8];
            s16x8 a1v = *(const s16x8*)&sh.f.A[g2][wm * 32 + 16 + l16][ks + quad * 8];
            s16x8 b0v = *(const s16x8*)&sh.f.B[g2][wn * 32      + l16][ks + quad * 8];
            s16x8 b1v = *(const s16x8*)&sh.f.B[g2][wn * 32 + 16 + l16][ks + quad * 8];
            acc[0][0] = __builtin_amdgcn_mfma_f32_16x16x32_bf16(a0v, b0v, acc[0][0], 0, 0, 0);
            acc[0][1] = __builtin_amdgcn_mfma_f32_16x16x32_bf16(a0v, b1v, acc[0][1], 0, 0, 0);
            acc[1][0] = __builtin_amdgcn_mfma_f32_16x16x32_bf16(a1v, b0v, acc[1][0], 0, 0, 0);
            acc[1][1] = __builtin_amdgcn_mfma_f32_16x16x32_bf16(a1v, b1v, acc[1][1], 0, 0, 0);
          }
        }

        __syncthreads();
        if (g2 == 1) {
          #pragma unroll
          for (int mi = 0; mi < 2; ++mi)
            #pragma unroll
            for (int ni = 0; ni < 2; ++ni)
              #pragma unroll
              for (int r = 0; r < 4; ++r)
                sh.fs[wm * 32 + mi * 16 + quad * 4 + r][wn * 32 + ni * 16 + l16] =
                    acc[mi][ni][r];
        }
        __syncthreads();
        if (g2 == 0) {
          #pragma unroll
          for (int mi = 0; mi < 2; ++mi) {
            #pragma unroll
            for (int ni = 0; ni < 2; ++ni) {
              #pragma unroll
              for (int r = 0; r < 4; ++r) {
                int ml = wm * 32 + mi * 16 + quad * 4 + r;
                int nl = wn * 32 + ni * 16 + l16;
                int m = m0 + ml;
                int n = n0 + nl;
                if (n < FCOUT) {
                  float rv = fmaxf(acc[mi][ni][r] + sh.fs[ml][nl] + b_fc[n], 0.f);
                  float msk = (t < length[m]) ? 1.f : 0.f;
                  if (n < L_) {
                    out[(size_t)m * (T_ * L_) + t * L_ + n] = rv * msk;
                  } else if (n < L_ + H_) {
                    out[(size_t)(B_ * T_ * L_) + (size_t)m * (T_ * H_) + t * H_ + (n - L_)] = rv * msk;
                  } else if (n == L_ + H_) {
                    out[(size_t)B_ * T_ * (L_ + H_) + m * T_ + t] = expf(rv) * msk;
                  } else {
                    out[(size_t)B_ * T_ * (L_ + H_ + 1) + m * T_ + t] = sigm(rv) * msk;
                  }
                }
              }
            }
          }
        }
      } else if (n0 == 0) {
        // dead tile: one block per m0 writes the zeros for all outputs
        f32x4 z = {0.f, 0.f, 0.f, 0.f};
        for (int i = tid; i < 64 * 32; i += 512) {          // label: 64 x 128
          int r = i >> 5, c4 = (i & 31) * 4;
          *(f32x4*)&out[(size_t)(m0 + r) * (T_ * L_) + t * L_ + c4] = z;
        }
        for (int i = tid; i < 64 * 256; i += 512) {         // topic: 64 x 1024
          int r = i >> 8, c4 = (i & 255) * 4;
          *(f32x4*)&out[(size_t)(B_ * T_ * L_) + (size_t)(m0 + r) * (T_ * H_) + t * H_ + c4] = z;
        }
        if (tid < 64) {
          out[(size_t)B_ * T_ * (L_ + H_) + (m0 + tid) * T_ + t] = 0.f;
          out[(size_t)B_ * T_ * (L_ + H_ + 1) + (m0 + tid) * T_ + t] = 0.f;
        }
      }
    }

    gbar(barCnt, p);
  }
}

// ---------------------------------------------------------------------------
extern "C" void kernel_launch(void* const* d_in, const int* in_sizes, int n_in,
                              void* d_out, int out_size, void* d_ws, size_t ws_size,
                              hipStream_t stream) {
  const float* image  = (const float*)d_in[0];
  const float* label  = (const float*)d_in[1];
  const int*   length = (const int*)  d_in[2];
  const float* W_h    = (const float*)d_in[3];
  const float* b_h    = (const float*)d_in[4];
  const float* W_m    = (const float*)d_in[5];
  const float* b_m    = (const float*)d_in[6];
  const float* W_ih   = (const float*)d_in[7];
  const float* W_hh   = (const float*)d_in[8];
  const float* b_ih   = (const float*)d_in[9];
  const float* b_hh   = (const float*)d_in[10];
  const float* W_fc   = (const float*)d_in[11];
  const float* b_fc   = (const float*)d_in[12];
  float* out = (float*)d_out;

  char* ws = (char*)d_ws;
  size_t off = 0;
  auto alloc = [&](size_t bytes) -> void* {
    void* p = ws + off;
    off = (off + bytes + 255) & ~(size_t)255;
    return p;
  };
  u16*   meanB = (u16*)  alloc((size_t)B_ * E_ * 2);
  u16*   WhB   = (u16*)  alloc((size_t)H_ * E_ * 2);
  u16*   WmB   = (u16*)  alloc((size_t)H_ * E_ * 2);
  u16*   WihE  = (u16*)  alloc((size_t)4 * H_ * E_ * 2);
  u16*   WihL  = (u16*)  alloc((size_t)4 * H_ * L_ * 2);
  u16*   WhhB  = (u16*)  alloc((size_t)4 * H_ * H_ * 2);
  u16*   WfcB  = (u16*)  alloc((size_t)FCPAD * H_ * 2);
  u16*   labB  = (u16*)  alloc((size_t)B_ * T_ * L_ * 2);
  float* gbase = (float*)alloc((size_t)B_ * 4 * H_ * 4);
  u16*   hbuf0 = (u16*)  alloc((size_t)B_ * H_ * 2);
  u16*   hbuf1 = (u16*)  alloc((size_t)B_ * H_ * 2);
  float* mS    = (float*)alloc((size_t)B_ * H_ * 4);
  int*   bar   = (int*)  alloc(256);

  auto cvt = [&](const float* in, u16* o, int rows, int src_rows, int in_ld,
                 int in_off, int cols) {
    long total4 = (long)rows * cols / 4;
    int blocks = (int)((total4 + 255) / 256);
    cvt_bf16_v4<<<blocks, 256, 0, stream>>>(in, o, src_rows, in_ld, in_off,
                                            cols / 4, total4);
  };

  // --- setup: weight/label conversion to bf16 ---
  cvt(W_h,  WhB,  H_,     H_,     E_,      0,  E_);
  cvt(W_m,  WmB,  H_,     H_,     E_,      0,  E_);
  cvt(W_ih, WihE, 4 * H_, 4 * H_, E_ + L_, 0,  E_);   // columns [0, E)
  cvt(W_ih, WihL, 4 * H_, 4 * H_, E_ + L_, E_, L_);   // columns [E, E+L)
  cvt(W_hh, WhhB, 4 * H_, 4 * H_, H_,      0,  H_);
  cvt(W_fc, WfcB, FCPAD,  FCOUT,  H_,      0,  H_);   // zero-padded rows
  cvt(label, labB, B_, B_, T_ * L_, 0, T_ * L_);

  img_mean_k<<<(B_ * E_ / 4) / 256, 256, 0, stream>>>(image, meanB);

  // --- setup GEMMs ---
  gemm_nt<1><<<dim3(B_ / 64, H_ / 64), 256, 0, stream>>>(
      meanB, E_, WhB, E_, E_, b_h, nullptr, nullptr, hbuf0, H_);
  gemm_nt<2><<<dim3(B_ / 64, H_ / 64), 256, 0, stream>>>(
      meanB, E_, WmB, E_, E_, b_m, nullptr, mS, nullptr, H_);
  gemm_nt<0><<<dim3(B_ / 64, (4 * H_) / 64), 256, 0, stream>>>(
      meanB, E_, WihE, E_, E_, b_ih, b_hh, gbase, nullptr, 4 * H_);

  // --- barrier state init + persistent scan (single launch) ---
  hipMemsetAsync(bar, 0, 8, stream);
  scan_k<<<NBLK, 512, 0, stream>>>(
      labB, WihL, WhhB, WfcB, gbase, b_fc, hbuf0, hbuf1, mS, length, out, bar);
}